// Round 11
// baseline (94.844 us; speedup 1.0000x reference)
//
#include <hip/hip_runtime.h>
#include <math.h>

#define NB    16
#define NP    4096
#define CLOUD (NB * NP)        // 65536 points per cloud
#define XT    8                // x-tiles (16 rows) per wave -> 128 x-rows
#define YSPL  4                // y splits; grid 16x8x8 = 1024 blocks, 4 waves
#define YPS   (NP / YSPL)      // 1024 y per split
#define YT    (YPS / 16)       // 64 y-tiles per split

typedef _Float16 f16;
typedef _Float16 f16x8 __attribute__((ext_vector_type(8)));
typedef float    f32x4v __attribute__((ext_vector_type(4)));

// R10 post-mortem: mfma loop was fat (per-iter f16 packing + cndmask zeroing)
// and L2-latency exposed. Now prep emits ready fragments: h8[i] = f16x8
// {x,y,z,0,...} per point (identity layout). B-frag = ONE dwordx4 at lane&15
// -- lanes 16-63 load dup data whose k>=8 slices are killed by A's zeroed
// lanes>=16 (product needs A[k] != 0). Bias prestored negated (na=-.5||y||^2)
// -> C-splat = load + 3 movs. Explicit 1-ahead prefetch hides L2.
__global__ __launch_bounds__(256) void prep_kernel(
    const float* __restrict__ A1, const float* __restrict__ A2,
    f16x8* __restrict__ h8, float* __restrict__ na)
{
    const int i = blockIdx.x * 256 + threadIdx.x;     // 0 .. 2*CLOUD
    const int off = (i < CLOUD) ? i : i - CLOUD;
    const float* p = ((i < CLOUD) ? A1 : A2) + (size_t)off * 3;
    const f16 hx = (f16)p[0], hy = (f16)p[1], hz = (f16)p[2];
    h8[i] = (f16x8){hx, hy, hz, (f16)0.f,
                    (f16)0.f, (f16)0.f, (f16)0.f, (f16)0.f};
    const float fx = (float)hx, fy = (float)hy, fz = (float)hz;
    na[i] = -0.5f * (fx * fx + fy * fy + fz * fz);    // negated bias
}

// Wave: 8 x-tiles (128 rows) vs one y-split (1024 y). m = dot + na_y (bias in
// C); e = -(na_x + max m) = 0.5||x^-y^||^2 >= 0 exactly. C/D: col=lane&15,
// row=(lane>>4)*4+reg (m89). Data only in k=0..2 of lane-group 0.
__global__ __launch_bounds__(256, 4) void mfma_kernel(
    const f16x8* __restrict__ h8, const float* __restrict__ na,
    float* __restrict__ part)
{
    const int b  = blockIdx.x;
    const int xs = blockIdx.y;          // x-super: 512 rows
    const int z  = blockIdx.z;
    const int yq = z & 3, dir = z >> 2;

    const int tid = threadIdx.x, lane = tid & 63, w = tid >> 6;
    const int c = lane & 15;            // col (B/C) / row-within-tile (A)
    const int g = lane >> 4;

    const f16x8* hX = h8 + (size_t)dir * CLOUD + (size_t)b * NP;
    const f16x8* hY = h8 + (size_t)(dir ^ 1) * CLOUD + (size_t)b * NP + yq * YPS;
    const float* nY = na + (size_t)(dir ^ 1) * CLOUD + (size_t)b * NP + yq * YPS;

    const int xbase = xs * 512 + w * 128;

    // A-frags: row c of each x-tile; lanes >= 16 MUST be zero (k-kill).
    f16x8 afr[XT];
    #pragma unroll
    for (int t = 0; t < XT; ++t) {
        f16x8 a = (f16x8)(f16)0.f;
        if (lane < 16) a = hX[xbase + t * 16 + c];
        afr[t] = a;
    }

    float mx[XT][4];
    #pragma unroll
    for (int t = 0; t < XT; ++t)
        #pragma unroll
        for (int r = 0; r < 4; ++r) mx[t][r] = -3.3e38f;

    // Prefetched main loop: 2 y-tiles per iter.
    f16x8 b0 = hY[0 * 16 + c];          // unpredicated: dup loads, k-killed
    f16x8 b1 = hY[1 * 16 + c];
    float n0 = nY[0 * 16 + c];
    float n1 = nY[1 * 16 + c];
    for (int j = 0; j < YT; j += 2) {
        const int jn = (j + 2) & (YT - 1);      // clamped prefetch index
        const f16x8 pb0 = hY[jn * 16 + c];
        const f16x8 pb1 = hY[(jn + 1) * 16 + c];
        const float pn0 = nY[jn * 16 + c];
        const float pn1 = nY[(jn + 1) * 16 + c];

        const f32x4v c0 = {n0, n0, n0, n0};     // bias-in-C (already negated)
        const f32x4v c1 = {n1, n1, n1, n1};
        #pragma unroll
        for (int t = 0; t < XT; ++t) {
            const f32x4v d0 =
                __builtin_amdgcn_mfma_f32_16x16x32_f16(afr[t], b0, c0, 0, 0, 0);
            const f32x4v d1 =
                __builtin_amdgcn_mfma_f32_16x16x32_f16(afr[t], b1, c1, 0, 0, 0);
            #pragma unroll
            for (int r = 0; r < 4; ++r)
                mx[t][r] = fmaxf(fmaxf(mx[t][r], d0[r]), d1[r]);  // v_max3
        }
        b0 = pb0; b1 = pb1; n0 = pn0; n1 = pn1;
    }

    // Max over the 16 cols (lane bits 0..3), one store per x-row.
    float* pslice = part + (size_t)yq * (2 * CLOUD)
                  + (size_t)dir * CLOUD + (size_t)b * NP;
    #pragma unroll
    for (int t = 0; t < XT; ++t) {
        #pragma unroll
        for (int r = 0; r < 4; ++r) {
            float v = mx[t][r];
            v = fmaxf(v, __shfl_xor(v, 1, 64));
            v = fmaxf(v, __shfl_xor(v, 2, 64));
            v = fmaxf(v, __shfl_xor(v, 4, 64));
            v = fmaxf(v, __shfl_xor(v, 8, 64));
            if (c == 0)
                pslice[xbase + t * 16 + g * 4 + r] = v;   // row = t*16+g*4+r
        }
    }
}

// 128 blocks x 1024: max over 4 y-splits, e = -(na + m) >= 0, sqrt(2e), sum.
__global__ __launch_bounds__(1024) void reduce_kernel(
    const float* __restrict__ part, const float* __restrict__ na,
    float* __restrict__ out)
{
    const int i = blockIdx.x * 1024 + threadIdx.x;   // dir*CLOUD + b*NP + x
    const int S = 2 * CLOUD;
    const float m = fmaxf(fmaxf(part[i], part[S + i]),
                          fmaxf(part[2 * S + i], part[3 * S + i]));
    const float e = fmaxf(-(na[i] + m), 0.0f);       // = d_min / 2
    float s = sqrtf(2.0f * e);
    #pragma unroll
    for (int off = 32; off > 0; off >>= 1)
        s += __shfl_down(s, off, 64);

    __shared__ float ws[16];
    const int lane = threadIdx.x & 63;
    const int wid  = threadIdx.x >> 6;
    if (lane == 0) ws[wid] = s;
    __syncthreads();
    if (threadIdx.x == 0) {
        float t = 0.0f;
        #pragma unroll
        for (int v = 0; v < 16; ++v) t += ws[v];
        // out = (sum1+sum2) * 1000 / (2 * NB * NP); 1000/131072 exact in fp32.
        atomicAdd(out, t * 0.00762939453125f);
    }
}

extern "C" void kernel_launch(void* const* d_in, const int* in_sizes, int n_in,
                              void* d_out, int out_size, void* d_ws, size_t ws_size,
                              hipStream_t stream)
{
    const float* a1 = (const float*)d_in[0];  // [NB, NP, 3] fp32
    const float* a2 = (const float*)d_in[1];  // [NB, NP, 3] fp32
    float* out = (float*)d_out;

    // ws: h8 frags (2 MiB) | na (0.5 MiB) | part (2 MiB)
    f16x8* h8 = (f16x8*)d_ws;
    float* na = (float*)((char*)d_ws + (size_t)2 * CLOUD * 16);
    float* part = na + (size_t)2 * CLOUD;

    hipMemsetAsync(out, 0, sizeof(float), stream);   // d_out poisoned 0xAA

    prep_kernel<<<(2 * CLOUD) / 256, 256, 0, stream>>>(a1, a2, h8, na);

    dim3 grid(NB, NP / 512, 2 * YSPL);   // 16 x 8 x 8 = 1024 blocks (4 waves)
    mfma_kernel<<<grid, 256, 0, stream>>>(h8, na, part);

    reduce_kernel<<<(2 * CLOUD) / 1024, 1024, 0, stream>>>(part, na, out);
}

// Round 12
// 83.230 us; speedup vs baseline: 1.1395x; 1.1395x over previous
//
#include <hip/hip_runtime.h>
#include <math.h>

#define NB     16
#define NP     4096
#define CLOUD  (NB * NP)        // 65536 points per cloud
#define BXR    256              // x-rows per block (4 waves x 64)
#define YSPL   2
#define YPS    (NP / YSPL)      // 2048 y per split (32 KB LDS)
#define YTILES (YPS / 32)       // 64

typedef _Float16 f16;
typedef _Float16 f16x8  __attribute__((ext_vector_type(8)));
typedef float    f32x16 __attribute__((ext_vector_type(16)));

// R11 post-mortem: inner loop was L2-latency bound (dup global B-frags, L1
// thrash). Now: 32x32x16 MFMA (4x pairs per MFMA-cycle vs 16x16x32), B-frags
// from LDS (y-split staged once/block, shared by 4 waves), and the bias rides
// k=3 of the GEMM (A.k3=1, B.k3=(f16)(-.5||y||^2)) so the inner iter is just
// ds_read_b128 + 2 MFMA + 32 v_max. Layout-robust: data occupies identical
// (lane,elem) slots in A and B -> same k either way; A zeroed elsewhere kills
// all other K terms. C/D: col=lane&31, row=(reg&3)+8(reg>>2)+4(lane>>5) [m74].
__global__ __launch_bounds__(256, 4) void mfma_kernel(
    const float* __restrict__ A1, const float* __restrict__ A2,
    float* __restrict__ part)
{
    __shared__ f16x8 sy[YPS];   // 32 KB -> 4 blocks/CU
    const int b = blockIdx.x, xc = blockIdx.y, z = blockIdx.z;
    const int ys = z & 1, dir = z >> 1;
    const float* X = dir ? A2 : A1;
    const float* Y = dir ? A1 : A2;
    const int tid = threadIdx.x, lane = tid & 63, w = tid >> 6;
    const int col = lane & 31;

    // Stage y-split: f16 coords + f16 bias in elem 3, rest zero.
    const float* Yb = Y + ((size_t)b * NP + ys * YPS) * 3;
    for (int i = tid; i < YPS; i += 256) {
        const float fx = Yb[3 * i], fy = Yb[3 * i + 1], fz = Yb[3 * i + 2];
        const f16 hx = (f16)fx, hy = (f16)fy, hz = (f16)fz;
        const float xx = (float)hx, yy = (float)hy, zz = (float)hz;
        const f16 nah = (f16)(-0.5f * (xx * xx + yy * yy + zz * zz));
        sy[i] = (f16x8){hx, hy, hz, nah,
                        (f16)0.f, (f16)0.f, (f16)0.f, (f16)0.f};
    }

    // A-frags: 2 tiles x 32 rows; k=3 = 1.0 (picks up B's bias);
    // lanes >= 32 zero -> kills k>=8 garbage from B's duplicated lanes.
    const int xbase = xc * BXR + w * 64;
    const float* Xb = X + ((size_t)b * NP + xbase) * 3;
    f16x8 afr[2];
    #pragma unroll
    for (int t = 0; t < 2; ++t) {
        f16x8 a = (f16x8)(f16)0.f;
        if (lane < 32) {
            const float* p = Xb + (t * 32 + col) * 3;
            a = (f16x8){(f16)p[0], (f16)p[1], (f16)p[2], (f16)1.0f,
                        (f16)0.f, (f16)0.f, (f16)0.f, (f16)0.f};
        }
        afr[t] = a;
    }
    __syncthreads();

    f32x16 mx0, mx1;
    #pragma unroll
    for (int r = 0; r < 16; ++r) { mx0[r] = -3.3e38f; mx1[r] = -3.3e38f; }
    const f32x16 Z = {};   // pinned zero accumulator input

    f16x8 bc = sy[col];    // lanes 32-63 dup lanes 0-31 (k-killed by A)
    #pragma unroll 2
    for (int j = 0; j < YTILES; ++j) {
        const f16x8 bn = sy[((j + 1) & (YTILES - 1)) * 32 + col]; // 1-ahead
        const f32x16 d0 =
            __builtin_amdgcn_mfma_f32_32x32x16_f16(afr[0], bc, Z, 0, 0, 0);
        const f32x16 d1 =
            __builtin_amdgcn_mfma_f32_32x32x16_f16(afr[1], bc, Z, 0, 0, 0);
        #pragma unroll
        for (int r = 0; r < 16; ++r) {
            mx0[r] = fmaxf(mx0[r], d0[r]);
            mx1[r] = fmaxf(mx1[r], d1[r]);
        }
        bc = bn;
    }

    // Col-max: 5 shfl_xor rounds (masks stay inside each 32-lane half).
    float* pslice = part + (size_t)ys * (2 * CLOUD)
                  + (size_t)dir * CLOUD + (size_t)b * NP;
    #pragma unroll
    for (int t = 0; t < 2; ++t) {
        #pragma unroll
        for (int r = 0; r < 16; ++r) {
            float v = (t == 0) ? mx0[r] : mx1[r];
            v = fmaxf(v, __shfl_xor(v, 1, 64));
            v = fmaxf(v, __shfl_xor(v, 2, 64));
            v = fmaxf(v, __shfl_xor(v, 4, 64));
            v = fmaxf(v, __shfl_xor(v, 8, 64));
            v = fmaxf(v, __shfl_xor(v, 16, 64));
            if (col == 0) {
                const int row = (r & 3) + 8 * (r >> 2) + 4 * (lane >> 5);
                pslice[xbase + t * 32 + row] = v;   // m = dot - 0.5||y||^2
            }
        }
    }
}

// 128 blocks x 1024: m = max over 2 y-splits; na_x recomputed from raw coords
// (same f16 rounding as the A-frags); e = -(na+m) >= 0; sqrt(2e); sum.
__global__ __launch_bounds__(1024) void reduce_kernel(
    const float* __restrict__ A1, const float* __restrict__ A2,
    const float* __restrict__ part, float* __restrict__ out)
{
    const int i = blockIdx.x * 1024 + threadIdx.x;   // dir*CLOUD + b*NP + x
    const int rem = i & (CLOUD - 1);
    const float* p = ((i < CLOUD) ? A1 : A2) + (size_t)rem * 3;
    const f16 hx = (f16)p[0], hy = (f16)p[1], hz = (f16)p[2];
    const float xx = (float)hx, yy = (float)hy, zz = (float)hz;
    const float na = -0.5f * (xx * xx + yy * yy + zz * zz);
    const float m = fmaxf(part[i], part[2 * CLOUD + i]);
    const float e = fmaxf(-(na + m), 0.0f);          // = d_min / 2
    float s = sqrtf(2.0f * e);
    #pragma unroll
    for (int off = 32; off > 0; off >>= 1)
        s += __shfl_down(s, off, 64);

    __shared__ float ws[16];
    const int lane = threadIdx.x & 63;
    const int wid  = threadIdx.x >> 6;
    if (lane == 0) ws[wid] = s;
    __syncthreads();
    if (threadIdx.x == 0) {
        float t = 0.0f;
        #pragma unroll
        for (int v = 0; v < 16; ++v) t += ws[v];
        // out = (sum1+sum2) * 1000 / (2 * NB * NP); 1000/131072 exact in fp32.
        atomicAdd(out, t * 0.00762939453125f);
    }
}

extern "C" void kernel_launch(void* const* d_in, const int* in_sizes, int n_in,
                              void* d_out, int out_size, void* d_ws, size_t ws_size,
                              hipStream_t stream)
{
    const float* a1 = (const float*)d_in[0];  // [NB, NP, 3] fp32
    const float* a2 = (const float*)d_in[1];  // [NB, NP, 3] fp32
    float* out = (float*)d_out;
    float* part = (float*)d_ws;               // [YSPL][2*CLOUD] = 1 MB

    hipMemsetAsync(out, 0, sizeof(float), stream);   // d_out poisoned 0xAA

    dim3 grid(NB, NP / BXR, 2 * YSPL);   // 16 x 16 x 4 = 1024 blocks, 4/CU
    mfma_kernel<<<grid, 256, 0, stream>>>(a1, a2, part);

    reduce_kernel<<<(2 * CLOUD) / 1024, 1024, 0, stream>>>(a1, a2, part, out);
}

// Round 13
// 82.150 us; speedup vs baseline: 1.1545x; 1.0131x over previous
//
#include <hip/hip_runtime.h>
#include <math.h>

#define NB    16
#define NP    4096
#define CLOUD (NB * NP)      // 65536 points per cloud
#define BXR   128            // x-rows per block (4 waves x 32)

typedef _Float16 f16;
typedef _Float16 f16x4  __attribute__((ext_vector_type(4)));
typedef _Float16 f16x8  __attribute__((ext_vector_type(8)));
typedef float    f32x16 __attribute__((ext_vector_type(16)));

// R12 post-mortem: two x-tiles/wave doubled both the max-VALU (32/iter) and
// accumulator VGPRs (likely spills at the 128 cap). Now: ONE x-tile per wave,
// TWO y-tiles per iter -> 16 v_max3 per 2 MFMA (VALU halved), one f32x16
// accumulator. All 4096 y in 32 KB LDS as f16x4 {x,y,z,na} (bias rides k=3
// of the GEMM: A.k3=1, B.k3=(f16)(-.5||y||^2)); A lanes>=32 zero kill all
// garbage K-terms. Final min/sqrt/sum done in-kernel -> graph is just
// memset(4B) + this kernel; no workspace use at all.
// C/D layout: col=lane&31, row=(r&3)+8*(r>>2)+4*(lane>>5)  [m74/m101].
__global__ __launch_bounds__(256, 4) void chamfer_mfma_kernel(
    const float* __restrict__ A1, const float* __restrict__ A2,
    float* __restrict__ out)
{
    __shared__ f16x4 sy[NP];     // 32 KB -> 4 blocks/CU
    __shared__ float sacc[4];
    const int b   = blockIdx.x;
    const int xc  = blockIdx.y;  // x-chunk (NP/BXR = 32)
    const int dir = blockIdx.z;
    const float* X = dir ? A2 : A1;
    const float* Y = dir ? A1 : A2;

    const int tid  = threadIdx.x;
    const int lane = tid & 63;
    const int w    = tid >> 6;   // 0..3
    const int col  = lane & 31;
    const int g    = lane >> 5;  // half-wave

    // Stage ALL 4096 y: f16 coords + f16 bias (from rounded coords) in elem 3.
    const float* Yb = Y + (size_t)b * NP * 3;
    for (int i = tid; i < NP; i += 256) {
        const float fx = Yb[3 * i], fy = Yb[3 * i + 1], fz = Yb[3 * i + 2];
        const f16 hx = (f16)fx, hy = (f16)fy, hz = (f16)fz;
        const float xx = (float)hx, yy = (float)hy, zz = (float)hz;
        sy[i] = (f16x4){hx, hy, hz, (f16)(-0.5f * (xx * xx + yy * yy + zz * zz))};
    }

    // My wave's x-tile: rows xbase..xbase+31 (lane col -> row xbase+col; both
    // half-waves hold the same row's coords -> nax valid in every lane).
    const int xbase = xc * BXR + w * 32;
    const float* p = X + ((size_t)b * NP + xbase + col) * 3;
    const f16 ahx = (f16)p[0], ahy = (f16)p[1], ahz = (f16)p[2];
    const float axx = (float)ahx, ayy = (float)ahy, azz = (float)ahz;
    const float nax = -0.5f * (axx * axx + ayy * ayy + azz * azz);
    f16x8 afr = (f16x8)(f16)0.f;
    if (lane < 32)
        afr = (f16x8){ahx, ahy, ahz, (f16)1.0f,
                      (f16)0.f, (f16)0.f, (f16)0.f, (f16)0.f};
    __syncthreads();

    f32x16 mx;
    #pragma unroll
    for (int r = 0; r < 16; ++r) mx[r] = -3.3e38f;
    const f32x16 Z = {};

    // 64 iters x 2 y-tiles; 1-ahead prefetch of the next ds pair.
    f16x4 q0 = sy[col];
    f16x4 q1 = sy[32 + col];
    #pragma unroll 2
    for (int j = 0; j < NP / 64; ++j) {
        const int jn = (j + 1) & (NP / 64 - 1);
        const f16x4 p0 = sy[jn * 64 + col];
        const f16x4 p1 = sy[jn * 64 + 32 + col];
        const f16x8 b0 = (f16x8){q0.x, q0.y, q0.z, q0.w,
                                 (f16)0.f, (f16)0.f, (f16)0.f, (f16)0.f};
        const f16x8 b1 = (f16x8){q1.x, q1.y, q1.z, q1.w,
                                 (f16)0.f, (f16)0.f, (f16)0.f, (f16)0.f};
        const f32x16 d0 =
            __builtin_amdgcn_mfma_f32_32x32x16_f16(afr, b0, Z, 0, 0, 0);
        const f32x16 d1 =
            __builtin_amdgcn_mfma_f32_32x32x16_f16(afr, b1, Z, 0, 0, 0);
        #pragma unroll
        for (int r = 0; r < 16; ++r)
            mx[r] = fmaxf(fmaxf(mx[r], d0[r]), d1[r]);   // v_max3_f32
        q0 = p0; q1 = p1;
    }

    // Col-max within each 32-lane half (cols live on lane bits 0..4).
    #pragma unroll
    for (int r = 0; r < 16; ++r) {
        float v = mx[r];
        v = fmaxf(v, __shfl_xor(v, 1, 64));
        v = fmaxf(v, __shfl_xor(v, 2, 64));
        v = fmaxf(v, __shfl_xor(v, 4, 64));
        v = fmaxf(v, __shfl_xor(v, 8, 64));
        v = fmaxf(v, __shfl_xor(v, 16, 64));
        mx[r] = v;   // all lanes of the half hold the row-(r,g) max
    }

    // Row (r,g) is owned by the lane with col == (r&3)+8*(r>>2)+4g, whose nax
    // matches that row. Sum sqrt(2e) with one contribution per row.
    float s = 0.0f;
    #pragma unroll
    for (int r = 0; r < 16; ++r) {
        const int target = (r & 3) + 8 * (r >> 2) + 4 * g;
        const float e = fmaxf(-(nax + mx[r]), 0.0f);     // = d_min/2, exact >= 0
        const float t = sqrtf(2.0f * e);
        s += (col == target) ? t : 0.0f;
    }
    #pragma unroll
    for (int off = 32; off > 0; off >>= 1)
        s += __shfl_down(s, off, 64);

    if (lane == 0) sacc[w] = s;
    __syncthreads();
    if (tid == 0) {
        const float t = (sacc[0] + sacc[1]) + (sacc[2] + sacc[3]);
        // out = (sum1+sum2) * 1000 / (2 * NB * NP); 1000/131072 exact in fp32.
        atomicAdd(out, t * 0.00762939453125f);
    }
}

extern "C" void kernel_launch(void* const* d_in, const int* in_sizes, int n_in,
                              void* d_out, int out_size, void* d_ws, size_t ws_size,
                              hipStream_t stream)
{
    const float* a1 = (const float*)d_in[0];  // [NB, NP, 3] fp32
    const float* a2 = (const float*)d_in[1];  // [NB, NP, 3] fp32
    float* out = (float*)d_out;

    hipMemsetAsync(out, 0, sizeof(float), stream);   // d_out poisoned 0xAA

    dim3 grid(NB, NP / BXR, 2);   // 16 x 32 x 2 = 1024 blocks, 4/CU
    chamfer_mfma_kernel<<<grid, 256, 0, stream>>>(a1, a2, out);
}

// Round 15
// 78.628 us; speedup vs baseline: 1.2062x; 1.0448x over previous
//
#include <hip/hip_runtime.h>
#include <math.h>

#define NB    16
#define NP    4096
#define CLOUD (NB * NP)      // 65536 points per cloud
#define BXR   128            // x-rows per block (4 waves x 32)
#define NBLK  (NB * (NP / BXR) * 2)   // 1024 blocks

typedef _Float16 f16;
typedef _Float16 f16x4  __attribute__((ext_vector_type(4)));
typedef _Float16 f16x8  __attribute__((ext_vector_type(8)));
typedef float    f32x16 __attribute__((ext_vector_type(16)));

// R13 post-mortem: kernel stuck ~35-40us across 4 different inner loops while
// per-pipe model says ~10us -> binder is the 2048 SAME-ADDRESS atomicAdd tail
// (uniform blocks finish in cohorts; same-address fp32 RMW serializes at the
// L2 coherence point, ~25-40ns each). This round changes ONLY the result
// path: per-block slot store + tiny reduce kernel (A/B test of that theory).
// Inner loop unchanged: bias rides k=3 of the GEMM (A.k3=1, B.k3=-.5||y||^2),
// A lanes>=32 zero kill garbage K-terms; 2 MFMA + 16 v_max3 per 64 y.
// C/D layout: col=lane&31, row=(r&3)+8*(r>>2)+4*(lane>>5)  [m74/m101].
__global__ __launch_bounds__(256, 4) void chamfer_mfma_kernel(
    const float* __restrict__ A1, const float* __restrict__ A2,
    float* __restrict__ part)
{
    __shared__ f16x4 sy[NP];     // 32 KB -> 4 blocks/CU
    __shared__ float sacc[4];
    const int b   = blockIdx.x;
    const int xc  = blockIdx.y;  // x-chunk (NP/BXR = 32)
    const int dir = blockIdx.z;
    const float* X = dir ? A2 : A1;
    const float* Y = dir ? A1 : A2;

    const int tid  = threadIdx.x;
    const int lane = tid & 63;
    const int w    = tid >> 6;   // 0..3
    const int col  = lane & 31;
    const int g    = lane >> 5;  // half-wave

    // Stage ALL 4096 y: f16 coords + f16 bias (from rounded coords) in elem 3.
    const float* Yb = Y + (size_t)b * NP * 3;
    for (int i = tid; i < NP; i += 256) {
        const float fx = Yb[3 * i], fy = Yb[3 * i + 1], fz = Yb[3 * i + 2];
        const f16 hx = (f16)fx, hy = (f16)fy, hz = (f16)fz;
        const float xx = (float)hx, yy = (float)hy, zz = (float)hz;
        sy[i] = (f16x4){hx, hy, hz, (f16)(-0.5f * (xx * xx + yy * yy + zz * zz))};
    }

    // My wave's x-tile: rows xbase..xbase+31 (lane col -> row xbase+col).
    const int xbase = xc * BXR + w * 32;
    const float* p = X + ((size_t)b * NP + xbase + col) * 3;
    const f16 ahx = (f16)p[0], ahy = (f16)p[1], ahz = (f16)p[2];
    const float axx = (float)ahx, ayy = (float)ahy, azz = (float)ahz;
    const float nax = -0.5f * (axx * axx + ayy * ayy + azz * azz);
    f16x8 afr = (f16x8)(f16)0.f;
    if (lane < 32)
        afr = (f16x8){ahx, ahy, ahz, (f16)1.0f,
                      (f16)0.f, (f16)0.f, (f16)0.f, (f16)0.f};
    __syncthreads();

    f32x16 mx;
    #pragma unroll
    for (int r = 0; r < 16; ++r) mx[r] = -3.3e38f;
    const f32x16 Z = {};

    // 64 iters x 2 y-tiles; 1-ahead prefetch of the next ds pair.
    f16x4 q0 = sy[col];
    f16x4 q1 = sy[32 + col];
    #pragma unroll 2
    for (int j = 0; j < NP / 64; ++j) {
        const int jn = (j + 1) & (NP / 64 - 1);
        const f16x4 p0 = sy[jn * 64 + col];
        const f16x4 p1 = sy[jn * 64 + 32 + col];
        const f16x8 b0 = (f16x8){q0.x, q0.y, q0.z, q0.w,
                                 (f16)0.f, (f16)0.f, (f16)0.f, (f16)0.f};
        const f16x8 b1 = (f16x8){q1.x, q1.y, q1.z, q1.w,
                                 (f16)0.f, (f16)0.f, (f16)0.f, (f16)0.f};
        const f32x16 d0 =
            __builtin_amdgcn_mfma_f32_32x32x16_f16(afr, b0, Z, 0, 0, 0);
        const f32x16 d1 =
            __builtin_amdgcn_mfma_f32_32x32x16_f16(afr, b1, Z, 0, 0, 0);
        #pragma unroll
        for (int r = 0; r < 16; ++r)
            mx[r] = fmaxf(fmaxf(mx[r], d0[r]), d1[r]);   // v_max3_f32
        q0 = p0; q1 = p1;
    }

    // Col-max within each 32-lane half (cols live on lane bits 0..4).
    #pragma unroll
    for (int r = 0; r < 16; ++r) {
        float v = mx[r];
        v = fmaxf(v, __shfl_xor(v, 1, 64));
        v = fmaxf(v, __shfl_xor(v, 2, 64));
        v = fmaxf(v, __shfl_xor(v, 4, 64));
        v = fmaxf(v, __shfl_xor(v, 8, 64));
        v = fmaxf(v, __shfl_xor(v, 16, 64));
        mx[r] = v;
    }

    // Row (r,g) owned by lane with col == (r&3)+8*(r>>2)+4g (its nax matches).
    float s = 0.0f;
    #pragma unroll
    for (int r = 0; r < 16; ++r) {
        const int target = (r & 3) + 8 * (r >> 2) + 4 * g;
        const float e = fmaxf(-(nax + mx[r]), 0.0f);     // = d_min/2, >= 0
        const float t = sqrtf(2.0f * e);
        s += (col == target) ? t : 0.0f;
    }
    #pragma unroll
    for (int off = 32; off > 0; off >>= 1)
        s += __shfl_down(s, off, 64);

    if (lane == 0) sacc[w] = s;
    __syncthreads();
    if (tid == 0) {
        // Per-block slot store -- NO same-address atomic.
        const int bid = blockIdx.x + NB * (blockIdx.y + (NP / BXR) * blockIdx.z);
        part[bid] = (sacc[0] + sacc[1]) + (sacc[2] + sacc[3]);
    }
}

// One block: sum the 1024 per-block partials, write out[0] directly.
__global__ __launch_bounds__(1024) void final_reduce_kernel(
    const float* __restrict__ part, float* __restrict__ out)
{
    float s = part[threadIdx.x];   // NBLK == 1024
    #pragma unroll
    for (int off = 32; off > 0; off >>= 1)
        s += __shfl_down(s, off, 64);

    __shared__ float ws[16];
    const int lane = threadIdx.x & 63;
    const int wid  = threadIdx.x >> 6;
    if (lane == 0) ws[wid] = s;
    __syncthreads();
    if (threadIdx.x == 0) {
        float t = 0.0f;
        #pragma unroll
        for (int v = 0; v < 16; ++v) t += ws[v];
        // out = (sum1+sum2) * 1000 / (2 * NB * NP); 1000/131072 exact in fp32.
        out[0] = t * 0.00762939453125f;
    }
}

extern "C" void kernel_launch(void* const* d_in, const int* in_sizes, int n_in,
                              void* d_out, int out_size, void* d_ws, size_t ws_size,
                              hipStream_t stream)
{
    const float* a1 = (const float*)d_in[0];  // [NB, NP, 3] fp32
    const float* a2 = (const float*)d_in[1];  // [NB, NP, 3] fp32
    float* out = (float*)d_out;
    float* part = (float*)d_ws;               // [NBLK] floats (4 KB)

    dim3 grid(NB, NP / BXR, 2);   // 16 x 32 x 2 = 1024 blocks, 4/CU
    chamfer_mfma_kernel<<<grid, 256, 0, stream>>>(a1, a2, part);

    final_reduce_kernel<<<1, 1024, 0, stream>>>(part, out);
}

// Round 16
// 74.288 us; speedup vs baseline: 1.2767x; 1.0584x over previous
//
#include <hip/hip_runtime.h>
#include <math.h>

#define NB    16
#define NP    4096
#define BXR   128            // x-rows per block (4 waves x 32)
#define NBLK  (NB * (NP / BXR) * 2)   // 1024 blocks

typedef _Float16 f16;
typedef _Float16 f16x4  __attribute__((ext_vector_type(4)));
typedef _Float16 f16x8  __attribute__((ext_vector_type(8)));
typedef float    f32x16 __attribute__((ext_vector_type(16)));

// R15 post-mortem: atomic tail was NOT the binder (-3.5us); the ~35us kernel
// residual is the 80-shfl column-reduce epilogue + per-iter zero-high movs.
// SWAPPED OPERANDS: A = y (iterating, from LDS), B = x (fixed). D col =
// lane&31 = lane's x-point [m74] -> min-over-y is LANE-LOCAL (mx[16] regs);
// row formula drops out (we max over all rows). Lane L and L+32 hold
// complementary row-subsets of the same col -> one shfl_xor(32) merges them.
// A's k>=4 slots are DON'T-CARE (B.k4..15 = 0 kills those products), so the
// LDS quad extends via shufflevector-undef -- no zeroing in the loop.
// Inner iter: 2 ds_read_b64 + 2 MFMA 32x32x16 + 16 v_max3. Bias rides k=3
// (A.k3 = -0.5||y||^2 from rounded coords, B.k3 = 1) -> e >= 0 exact.
__global__ __launch_bounds__(256, 4) void chamfer_mfma_kernel(
    const float* __restrict__ A1, const float* __restrict__ A2,
    float* __restrict__ part)
{
    __shared__ f16x4 sy[NP];     // 32 KB -> 4 blocks/CU
    __shared__ float sacc[4];
    const int b   = blockIdx.x;
    const int xc  = blockIdx.y;  // x-chunk (NP/BXR = 32)
    const int dir = blockIdx.z;
    const float* X = dir ? A2 : A1;
    const float* Y = dir ? A1 : A2;

    const int tid  = threadIdx.x;
    const int lane = tid & 63;
    const int w    = tid >> 6;   // 0..3
    const int col  = lane & 31;

    // Stage ALL 4096 y: f16 coords + f16 bias (from rounded coords) in elem 3.
    const float* Yb = Y + (size_t)b * NP * 3;
    for (int i = tid; i < NP; i += 256) {
        const float fx = Yb[3 * i], fy = Yb[3 * i + 1], fz = Yb[3 * i + 2];
        const f16 hx = (f16)fx, hy = (f16)fy, hz = (f16)fz;
        const float xx = (float)hx, yy = (float)hy, zz = (float)hz;
        sy[i] = (f16x4){hx, hy, hz, (f16)(-0.5f * (xx * xx + yy * yy + zz * zz))};
    }

    // B-frag: my x-point (col) in k=0..3 of lanes<32; EVERYTHING else zero
    // (this is what makes A's k>=4 and lanes>=32 content don't-care).
    const int xbase = xc * BXR + w * 32;
    const float* p = X + ((size_t)b * NP + xbase + col) * 3;
    const f16 ahx = (f16)p[0], ahy = (f16)p[1], ahz = (f16)p[2];
    const float axx = (float)ahx, ayy = (float)ahy, azz = (float)ahz;
    const float nax = -0.5f * (axx * axx + ayy * ayy + azz * azz);
    f16x8 bfr = (f16x8)(f16)0.f;
    if (lane < 32)
        bfr = (f16x8){ahx, ahy, ahz, (f16)1.0f,
                      (f16)0.f, (f16)0.f, (f16)0.f, (f16)0.f};
    __syncthreads();

    f32x16 mx;
    #pragma unroll
    for (int r = 0; r < 16; ++r) mx[r] = -3.3e38f;
    const f32x16 Z = {};

    // 64 iters x 2 y-tiles; 1-ahead ds prefetch. Lanes 32-63 dup-read (ok).
    f16x4 q0 = sy[col];
    f16x4 q1 = sy[32 + col];
    #pragma unroll 2
    for (int j = 0; j < NP / 64; ++j) {
        const int jn = (j + 1) & (NP / 64 - 1);
        const f16x4 p0 = sy[jn * 64 + col];
        const f16x4 p1 = sy[jn * 64 + 32 + col];
        const f16x8 a0 = __builtin_shufflevector(q0, q0, 0, 1, 2, 3, -1, -1, -1, -1);
        const f16x8 a1 = __builtin_shufflevector(q1, q1, 0, 1, 2, 3, -1, -1, -1, -1);
        const f32x16 d0 =
            __builtin_amdgcn_mfma_f32_32x32x16_f16(a0, bfr, Z, 0, 0, 0);
        const f32x16 d1 =
            __builtin_amdgcn_mfma_f32_32x32x16_f16(a1, bfr, Z, 0, 0, 0);
        #pragma unroll
        for (int r = 0; r < 16; ++r)
            mx[r] = fmaxf(fmaxf(mx[r], d0[r]), d1[r]);   // v_max3_f32
        q0 = p0; q1 = p1;
    }

    // Lane-local tree over the 16 row-regs (8 ops), then merge the
    // complementary half-wave rows (1 shfl), then e/sqrt/sum.
    #define F3(a, bb, c) fmaxf(fmaxf((a), (bb)), (c))
    const float t0 = F3(mx[0],  mx[1],  mx[2]);
    const float t1 = F3(mx[3],  mx[4],  mx[5]);
    const float t2 = F3(mx[6],  mx[7],  mx[8]);
    const float t3 = F3(mx[9],  mx[10], mx[11]);
    const float t4 = F3(mx[12], mx[13], mx[14]);
    float v = fmaxf(F3(t0, t1, t2), F3(t3, t4, mx[15]));
    #undef F3
    v = fmaxf(v, __shfl_xor(v, 32, 64));     // rows split across half-waves

    const float e = fmaxf(-(nax + v), 0.0f); // = d_min/2, exact >= 0
    float s = (lane < 32) ? sqrtf(2.0f * e) : 0.0f;   // count each x once
    #pragma unroll
    for (int off = 32; off > 0; off >>= 1)
        s += __shfl_down(s, off, 64);

    if (lane == 0) sacc[w] = s;
    __syncthreads();
    if (tid == 0) {
        const int bid = blockIdx.x + NB * (blockIdx.y + (NP / BXR) * blockIdx.z);
        part[bid] = (sacc[0] + sacc[1]) + (sacc[2] + sacc[3]);
    }
}

// One block: sum the 1024 per-block partials, write out[0] directly.
__global__ __launch_bounds__(1024) void final_reduce_kernel(
    const float* __restrict__ part, float* __restrict__ out)
{
    float s = part[threadIdx.x];   // NBLK == 1024
    #pragma unroll
    for (int off = 32; off > 0; off >>= 1)
        s += __shfl_down(s, off, 64);

    __shared__ float ws[16];
    const int lane = threadIdx.x & 63;
    const int wid  = threadIdx.x >> 6;
    if (lane == 0) ws[wid] = s;
    __syncthreads();
    if (threadIdx.x == 0) {
        float t = 0.0f;
        #pragma unroll
        for (int v = 0; v < 16; ++v) t += ws[v];
        // out = (sum1+sum2) * 1000 / (2 * NB * NP); 1000/131072 exact in fp32.
        out[0] = t * 0.00762939453125f;
    }
}

extern "C" void kernel_launch(void* const* d_in, const int* in_sizes, int n_in,
                              void* d_out, int out_size, void* d_ws, size_t ws_size,
                              hipStream_t stream)
{
    const float* a1 = (const float*)d_in[0];  // [NB, NP, 3] fp32
    const float* a2 = (const float*)d_in[1];  // [NB, NP, 3] fp32
    float* out = (float*)d_out;
    float* part = (float*)d_ws;               // [NBLK] floats (4 KB)

    dim3 grid(NB, NP / BXR, 2);   // 16 x 32 x 2 = 1024 blocks, 4/CU
    chamfer_mfma_kernel<<<grid, 256, 0, stream>>>(a1, a2, part);

    final_reduce_kernel<<<1, 1024, 0, stream>>>(part, out);
}